// Round 4
// baseline (197.550 us; speedup 1.0000x reference)
//
#include <hip/hip_runtime.h>
#include <hip/hip_bf16.h>

typedef __bf16 bf16_t;
typedef __attribute__((ext_vector_type(8))) __bf16 bf16x8;
typedef __attribute__((ext_vector_type(4))) __bf16 bf16x4;
typedef __attribute__((ext_vector_type(4))) float f32x4;

#define MFMA16(a, b, c) __builtin_amdgcn_mfma_f32_16x16x32_bf16((a), (b), (c), 0, 0, 0)

// ---------------------------------------------------------------------------
// Kernel 1: QKV projection with T14 reg-prefetch of the X slab.
// Out[m][n] = sum_k X[m][k]*W[n][k]; Q pre-scaled by 1/sqrt(H); V transposed.
// ---------------------------------------------------------------------------
__global__ __launch_bounds__(256, 3) void proj_qkv(
    const float* __restrict__ X,
    const float* __restrict__ W0, const float* __restrict__ W1, const float* __restrict__ W2,
    bf16_t* __restrict__ O0, bf16_t* __restrict__ O1, bf16_t* __restrict__ O2)
{
    __shared__ __align__(16) char As[128 * 128];
    __shared__ __align__(16) char Bs[128 * 128];

    const int tid = threadIdx.x;
    const int wid = tid >> 6;
    const int lane = tid & 63;
    const int l15 = lane & 15, l4 = lane >> 4;
    const int wr = wid >> 1, wc = wid & 1;
    const int m0 = blockIdx.x * 128;

    const float* W = (blockIdx.y == 0) ? W0 : (blockIdx.y == 1 ? W1 : W2);

    // Per-thread staging coords: row r0 + 16*i, float4-chunk kq (constant).
    const int r0 = tid >> 4;
    const int kq = tid & 15;
    const int swz = ((r0 & 7) << 4);   // (r0+16i)&7 == r0&7

    f32x4 acc[4][4] = {};
    float4 xr[8];

    // Prefetch X slab for kb=0.
    #pragma unroll
    for (int i = 0; i < 8; ++i)
        xr[i] = *(const float4*)(X + (size_t)(m0 + r0 + i * 16) * 1024 + kq * 4);

    for (int ks = 0; ks < 16; ++ks) {
        const int kb = ks * 64;
        // STORE phase: X from prefetch regs; W loaded+converted here (L2-hot).
        #pragma unroll
        for (int i = 0; i < 8; ++i) {
            const int r = r0 + i * 16;
            bf16x4 av; av[0] = (bf16_t)xr[i].x; av[1] = (bf16_t)xr[i].y;
            av[2] = (bf16_t)xr[i].z; av[3] = (bf16_t)xr[i].w;
            *(bf16x4*)(As + r * 128 + ((kq * 8) ^ swz)) = av;
        }
        #pragma unroll
        for (int i = 0; i < 8; ++i) {
            const int r = r0 + i * 16;
            float4 wa = *(const float4*)(W + (size_t)r * 1024 + kb + kq * 4);
            bf16x4 wv; wv[0] = (bf16_t)wa.x; wv[1] = (bf16_t)wa.y;
            wv[2] = (bf16_t)wa.z; wv[3] = (bf16_t)wa.w;
            *(bf16x4*)(Bs + r * 128 + ((kq * 8) ^ swz)) = wv;
        }
        __syncthreads();
        // Issue next X slab now; lands during MFMA compute.
        if (ks < 15) {
            #pragma unroll
            for (int i = 0; i < 8; ++i)
                xr[i] = *(const float4*)(X + (size_t)(m0 + r0 + i * 16) * 1024 + kb + 64 + kq * 4);
        }
        #pragma unroll
        for (int kk = 0; kk < 64; kk += 32) {
            const int kbyte = 2 * kk + 16 * l4;
            bf16x8 af[4], bfr[4];
            #pragma unroll
            for (int mi = 0; mi < 4; ++mi) {
                int r = wr * 64 + mi * 16 + l15;
                af[mi] = *(const bf16x8*)(As + r * 128 + (kbyte ^ ((r & 7) << 4)));
            }
            #pragma unroll
            for (int ni = 0; ni < 4; ++ni) {
                int r = wc * 64 + ni * 16 + l15;
                bfr[ni] = *(const bf16x8*)(Bs + r * 128 + (kbyte ^ ((r & 7) << 4)));
            }
            #pragma unroll
            for (int mi = 0; mi < 4; ++mi)
                #pragma unroll
                for (int ni = 0; ni < 4; ++ni)
                    acc[mi][ni] = MFMA16(af[mi], bfr[ni], acc[mi][ni]);
        }
        __syncthreads();
    }

    if (blockIdx.y < 2) {
        const float sc = (blockIdx.y == 0) ? 0.08838834764831845f : 1.0f;
        bf16_t* O = (blockIdx.y == 0) ? O0 : O1;
        #pragma unroll
        for (int mi = 0; mi < 4; ++mi)
            #pragma unroll
            for (int ni = 0; ni < 4; ++ni) {
                int row = m0 + wr * 64 + mi * 16 + l4 * 4;
                int col = wc * 64 + ni * 16 + l15;
                #pragma unroll
                for (int r = 0; r < 4; ++r)
                    O[(size_t)(row + r) * 128 + col] = (bf16_t)(acc[mi][ni][r] * sc);
            }
    } else {
        #pragma unroll
        for (int mi = 0; mi < 4; ++mi)
            #pragma unroll
            for (int ni = 0; ni < 4; ++ni) {
                int row0 = m0 + wr * 64 + mi * 16 + l4 * 4;
                int col = wc * 64 + ni * 16 + l15;
                int bb = row0 >> 12, t0 = row0 & 4095;
                bf16x4 pk;
                #pragma unroll
                for (int r = 0; r < 4; ++r) pk[r] = (bf16_t)acc[mi][ni][r];
                *(bf16x4*)(O2 + ((size_t)bb << 19) + (size_t)col * 4096 + t0) = pk;
            }
    }
}

// ---------------------------------------------------------------------------
// Kernel 2: causal flash attention, split-kv pairs + T14 reg-prefetch.
// 4 waves = 2 pairs (even/odd 64-kv tiles), 32 q-rows/wave, S^T = K*Q^T.
// Next tile loaded into regs BEFORE compute; LDS write after the barrier.
// ---------------------------------------------------------------------------
__global__ __launch_bounds__(256, 2) void attn_fwd(
    const bf16_t* __restrict__ Qb, const bf16_t* __restrict__ Kb,
    const bf16_t* __restrict__ Vtg, float* __restrict__ out, int Bn)
{
    // [0,16K) KsA | [16K,32K) VtA | [32K,48K) KsB | [48K,64K) VtB | [64K,80K) P(4K/wave)
    __shared__ __align__(16) char lds[81920];

    const int tid = threadIdx.x, wid = tid >> 6, lane = tid & 63;
    const int l15 = lane & 15, l4 = lane >> 4;
    const int pair = wid >> 1;
    const int qhalf = wid & 1;

    const int L = blockIdx.x;
    const int b = L % Bn;
    const int j = L / Bn;
    const int qt = (j < 32) ? j : 95 - j;
    const int q0 = qt << 6;
    const int steps = (qt >> 1) + 1;
    const int qw0 = q0 + 32 * qhalf;

    const size_t base = (size_t)b * 4096 * 128;

    bf16x8 aq[2][4];
    #pragma unroll
    for (int qs = 0; qs < 2; ++qs)
        #pragma unroll
        for (int kf = 0; kf < 4; ++kf)
            aq[qs][kf] = *(const bf16x8*)(Qb + base + (size_t)(qw0 + 16 * qs + l15) * 128 + 32 * kf + 8 * l4);

    float mx[2] = {-1e30f, -1e30f}, lsum[2] = {0.f, 0.f};
    f32x4 o[2][8] = {};

    char* Kbuf = lds + pair * 32768;
    char* Vbuf = Kbuf + 16384;
    char* Pw   = lds + 65536 + wid * 4096;
    char* stg  = lds + wid * 16384;      // w0:KsA w1:VtA w2:KsB w3:VtB

    const bool isK = (wid & 1) == 0;
    const int Kr0 = lane >> 4, Kc = (lane & 15) << 4;   // byte col
    const int Vr0 = lane >> 3, Vc = (lane & 7) << 4;
    bf16x8 pf[16];

    auto validt = [&](int s) { return (2 * s + pair) * 64 <= q0 + 63; };

    auto LOADT = [&](int s) {
        const int kv0s = (2 * s + pair) << 6;
        if (isK) {
            #pragma unroll
            for (int i = 0; i < 16; ++i) {
                const int row = i * 4 + Kr0;
                pf[i] = *(const bf16x8*)(Kb + base + (size_t)(kv0s + row) * 128 + (Kc >> 1));
            }
        } else {
            #pragma unroll
            for (int i = 0; i < 16; ++i) {
                const int h = i * 8 + Vr0;
                pf[i] = *(const bf16x8*)(Vtg + base + (size_t)h * 4096 + kv0s + (Vc >> 1));
            }
        }
    };
    auto WRITET = [&]() {
        if (isK) {
            #pragma unroll
            for (int i = 0; i < 16; ++i) {
                const int row = i * 4 + Kr0;
                *(bf16x8*)(stg + row * 256 + (Kc ^ ((row & 7) << 4))) = pf[i];
            }
        } else {
            const int swz = (Vr0 & 7) << 4;   // (i*8+Vr0)&7 == Vr0&7
            #pragma unroll
            for (int i = 0; i < 16; ++i)
                *(bf16x8*)(stg + (i * 8 + Vr0) * 128 + (Vc ^ swz)) = pf[i];
        }
    };

    if (validt(0)) { LOADT(0); WRITET(); }
    __syncthreads();

    for (int s = 0; s < steps; ++s) {
        const int kv0 = (2 * s + pair) << 6;
        const bool nxt = (s + 1 < steps);
        if (nxt && validt(s + 1)) LOADT(s + 1);   // regs: no LDS hazard, flies under compute

        if (kv0 <= qw0 + 31) {
            f32x4 sa[2][4];
            #pragma unroll
            for (int qs = 0; qs < 2; ++qs)
                #pragma unroll
                for (int ni = 0; ni < 4; ++ni) sa[qs][ni] = (f32x4){0.f, 0.f, 0.f, 0.f};
            #pragma unroll
            for (int kf = 0; kf < 4; ++kf) {
                const int kb = 64 * kf + 16 * l4;
                #pragma unroll
                for (int ni = 0; ni < 4; ++ni) {
                    const int krow = 16 * ni + l15;
                    bf16x8 ak = *(const bf16x8*)(Kbuf + krow * 256 + (kb ^ ((krow & 7) << 4)));
                    sa[0][ni] = MFMA16(ak, aq[0][kf], sa[0][ni]);
                    sa[1][ni] = MFMA16(ak, aq[1][kf], sa[1][ni]);
                }
            }
            #pragma unroll
            for (int qs = 0; qs < 2; ++qs) {
                const int qg = qw0 + 16 * qs + l15;
                if (kv0 + 63 > qw0 + 16 * qs) {
                    #pragma unroll
                    for (int ni = 0; ni < 4; ++ni)
                        #pragma unroll
                        for (int r = 0; r < 4; ++r)
                            if (kv0 + 16 * ni + 4 * l4 + r > qg) sa[qs][ni][r] = -1e30f;
                }
                float tm = sa[qs][0][0];
                #pragma unroll
                for (int ni = 0; ni < 4; ++ni)
                    #pragma unroll
                    for (int r = 0; r < 4; ++r) tm = fmaxf(tm, sa[qs][ni][r]);
                tm = fmaxf(tm, __shfl_xor(tm, 16, 64));
                tm = fmaxf(tm, __shfl_xor(tm, 32, 64));
                const float mnew = fmaxf(mx[qs], tm);
                const float c = __expf(mx[qs] - mnew);
                float ssum = 0.f;
                #pragma unroll
                for (int ni = 0; ni < 4; ++ni)
                    #pragma unroll
                    for (int r = 0; r < 4; ++r) {
                        float pv = __expf(sa[qs][ni][r] - mnew);
                        sa[qs][ni][r] = pv;
                        ssum += pv;
                    }
                ssum += __shfl_xor(ssum, 16, 64);
                ssum += __shfl_xor(ssum, 32, 64);
                lsum[qs] = lsum[qs] * c + ssum;
                mx[qs] = mnew;
                #pragma unroll
                for (int mf = 0; mf < 8; ++mf) {
                    f32x4 t = o[qs][mf];
                    t[0] *= c; t[1] *= c; t[2] *= c; t[3] *= c;
                    o[qs][mf] = t;
                }
                const int rowb = (16 * qs + l15) * 128;
                const int swzp = (l15 & 7) << 4;
                #pragma unroll
                for (int ni = 0; ni < 4; ++ni) {
                    bf16x4 pv;
                    pv[0] = (bf16_t)sa[qs][ni][0]; pv[1] = (bf16_t)sa[qs][ni][1];
                    pv[2] = (bf16_t)sa[qs][ni][2]; pv[3] = (bf16_t)sa[qs][ni][3];
                    *(bf16x4*)(Pw + rowb + ((32 * ni + 8 * l4) ^ swzp)) = pv;
                }
            }
            const int swzp = (l15 & 7) << 4;
            #pragma unroll
            for (int kfp = 0; kfp < 2; ++kfp) {
                const int kb = 64 * kfp + 16 * l4;
                bf16x8 p0 = *(const bf16x8*)(Pw + l15 * 128 + (kb ^ swzp));
                bf16x8 p1 = *(const bf16x8*)(Pw + (16 + l15) * 128 + (kb ^ swzp));
                #pragma unroll
                for (int mf = 0; mf < 8; ++mf) {
                    const int h = 16 * mf + l15;
                    bf16x8 av = *(const bf16x8*)(Vbuf + h * 128 + (kb ^ ((h & 7) << 4)));
                    o[0][mf] = MFMA16(av, p0, o[0][mf]);
                    o[1][mf] = MFMA16(av, p1, o[1][mf]);
                }
            }
        }
        if (nxt) {
            __syncthreads();                 // all reads of current tiles done
            if (validt(s + 1)) WRITET();     // regs -> LDS (vmcnt wait auto)
            __syncthreads();                 // staged data visible
        }
    }

    // Merge pair B's online state into pair A's, then store.
    __syncthreads();
    if (wid >= 2) {
        char* dst = lds + (wid - 2) * 16384;
        #pragma unroll
        for (int qs = 0; qs < 2; ++qs)
            #pragma unroll
            for (int mf = 0; mf < 8; ++mf)
                *(f32x4*)(dst + (qs * 8 + mf) * 1024 + lane * 16) = o[qs][mf];
        f32x4 st; st[0] = mx[0]; st[1] = lsum[0]; st[2] = mx[1]; st[3] = lsum[1];
        *(f32x4*)(lds + 32768 + (wid - 2) * 1024 + lane * 16) = st;
    }
    __syncthreads();
    if (wid < 2) {
        char* srcO = lds + wid * 16384;
        f32x4 st = *(const f32x4*)(lds + 32768 + wid * 1024 + lane * 16);
        #pragma unroll
        for (int qs = 0; qs < 2; ++qs) {
            const float mB = st[2 * qs], lB = st[2 * qs + 1];
            const float mm = fmaxf(mx[qs], mB);
            const float a = __expf(mx[qs] - mm), bb = __expf(mB - mm);
            const float linv = 1.f / (lsum[qs] * a + lB * bb);
            const int qg = qw0 + 16 * qs + l15;
            float* op = out + ((size_t)b * 4096 + qg) * 128;
            #pragma unroll
            for (int mf = 0; mf < 8; ++mf) {
                f32x4 ob = *(const f32x4*)(srcO + (qs * 8 + mf) * 1024 + lane * 16);
                f32x4 r;
                #pragma unroll
                for (int e = 0; e < 4; ++e) r[e] = (o[qs][mf][e] * a + ob[e] * bb) * linv;
                *(f32x4*)(op + 16 * mf + 4 * l4) = r;
            }
        }
    }
}

extern "C" void kernel_launch(void* const* d_in, const int* in_sizes, int n_in,
                              void* d_out, int out_size, void* d_ws, size_t ws_size,
                              hipStream_t stream) {
    const float* X  = (const float*)d_in[0];
    const float* Wq = (const float*)d_in[1];
    const float* Wk = (const float*)d_in[2];
    const float* Wv = (const float*)d_in[3];
    float* out = (float*)d_out;

    const int M = in_sizes[0] / 1024;      // B*T
    const int Bn = M / 4096;               // 8

    bf16_t* Qb  = (bf16_t*)d_ws;
    bf16_t* KbP = Qb + (size_t)M * 128;
    bf16_t* VtP = KbP + (size_t)M * 128;   // transposed: [b][128][4096]

    proj_qkv<<<dim3(M / 128, 3), 256, 0, stream>>>(X, Wq, Wk, Wv, Qb, KbP, VtP);
    attn_fwd<<<dim3(64 * Bn), 256, 0, stream>>>(Qb, KbP, VtP, out, Bn);
}